// Round 2
// baseline (159.662 us; speedup 1.0000x reference)
//
#include <hip/hip_runtime.h>
#include <math.h>

#define BB 4
#define RR 1024
#define NN 100
#define NROI (BB * RR)
#define NPAIR (NROI * NN)

// ws layout: [0..15] counter (int at 0) | [16 .. 16+NROI*8) best u64 | [list_off ...) survivor list (int)
#define BEST_OFF 16
#define LIST_OFF (BEST_OFF + NROI * 8)

// packed best: high 32 = float bits of IoU (>=0, monotone), low 32 = ~gt_idx
// => atomicMax picks highest IoU; on exact value tie, smallest gt index.
#define INIT_PACK 0x00000000FFFFFFFFull

__device__ __forceinline__ bool cheap_pass(const float a[7], const float b[7]) {
    float oh = fminf(a[2] + a[5] * 0.5f, b[2] + b[5] * 0.5f)
             - fmaxf(a[2] - a[5] * 0.5f, b[2] - b[5] * 0.5f);
    float dxc = a[0] - b[0], dyc = a[1] - b[1];
    float ra = 0.5f * sqrtf(a[3] * a[3] + a[4] * a[4]);
    float rb = 0.5f * sqrtf(b[3] * b[3] + b[4] * b[4]);
    float rr = ra + rb;
    return (oh > 0.0f) && (dxc * dxc + dyc * dyc <= rr * rr);
}

// Exact rotated-rect BEV intersection + 3D IoU — identical math to the R1 passing kernel.
__device__ float iou3d_pair(const float a[7], const float b[7]) {
    float oh = fminf(a[2] + a[5] * 0.5f, b[2] + b[5] * 0.5f)
             - fmaxf(a[2] - a[5] * 0.5f, b[2] - b[5] * 0.5f);
    float dxc = a[0] - b[0], dyc = a[1] - b[1];
    float ra = 0.5f * sqrtf(a[3] * a[3] + a[4] * a[4]);
    float rb = 0.5f * sqrtf(b[3] * b[3] + b[4] * b[4]);
    float rr = ra + rb;
    if (oh <= 0.0f || dxc * dxc + dyc * dyc > rr * rr) return 0.0f;

    float ac = cosf(a[6]), as_ = sinf(a[6]);
    float bc = cosf(b[6]), bs_ = sinf(b[6]);

    const float lxs[4] = {0.5f, -0.5f, -0.5f, 0.5f};
    const float lys[4] = {0.5f,  0.5f, -0.5f, -0.5f};
    float cax[4], cay[4], cbx[4], cby[4];
#pragma unroll
    for (int i = 0; i < 4; i++) {
        float lx = lxs[i] * a[3], ly = lys[i] * a[4];
        cax[i] = a[0] + lx * ac - ly * as_;
        cay[i] = a[1] + lx * as_ + ly * ac;
        float mx = lxs[i] * b[3], my = lys[i] * b[4];
        cbx[i] = b[0] + mx * bc - my * bs_;
        cby[i] = b[1] + mx * bs_ + my * bc;
    }

    float px[24], py[24];
    unsigned valid = 0u;

#pragma unroll
    for (int i = 0; i < 4; i++) {
        px[i] = cax[i]; py[i] = cay[i];
        float qx = cax[i] - b[0], qy = cay[i] - b[1];
        float lx = qx * bc + qy * bs_;
        float ly = -qx * bs_ + qy * bc;
        if (fabsf(lx) <= b[3] * 0.5f + 1e-5f && fabsf(ly) <= b[4] * 0.5f + 1e-5f)
            valid |= 1u << i;
    }
#pragma unroll
    for (int i = 0; i < 4; i++) {
        px[4 + i] = cbx[i]; py[4 + i] = cby[i];
        float qx = cbx[i] - a[0], qy = cby[i] - a[1];
        float lx = qx * ac + qy * as_;
        float ly = -qx * as_ + qy * ac;
        if (fabsf(lx) <= a[3] * 0.5f + 1e-5f && fabsf(ly) <= a[4] * 0.5f + 1e-5f)
            valid |= 1u << (4 + i);
    }
#pragma unroll
    for (int i = 0; i < 4; i++) {
        float a1x = cax[i], a1y = cay[i];
        float d1x = cax[(i + 1) & 3] - a1x, d1y = cay[(i + 1) & 3] - a1y;
#pragma unroll
        for (int j = 0; j < 4; j++) {
            float b1x = cbx[j], b1y = cby[j];
            float d2x = cbx[(j + 1) & 3] - b1x, d2y = cby[(j + 1) & 3] - b1y;
            float denom = d1x * d2y - d1y * d2x;
            float fx = b1x - a1x, fy = b1y - a1y;
            float safe = (fabsf(denom) > 1e-8f) ? denom : 1e-8f;
            float t = (fx * d2y - fy * d2x) / safe;
            float u = (fx * d1y - fy * d1x) / safe;
            int k = 8 + i * 4 + j;
            px[k] = a1x + t * d1x;
            py[k] = a1y + t * d1y;
            if (fabsf(denom) > 1e-8f && t >= 0.0f && t <= 1.0f && u >= 0.0f && u <= 1.0f)
                valid |= 1u << k;
        }
    }

    int nv = __popc(valid);
    float inter_bev = 0.0f;
    if (nv >= 3) {
        float sx = 0.0f, sy = 0.0f;
#pragma unroll
        for (int k = 0; k < 24; k++) {
            if ((valid >> k) & 1u) { sx += px[k]; sy += py[k]; }
        }
        float cx = sx / (float)nv, cy = sy / (float)nv;

        float ang[24];
#pragma unroll
        for (int k = 0; k < 24; k++) {
            ang[k] = ((valid >> k) & 1u) ? atan2f(py[k] - cy, px[k] - cx) : 1e9f;
        }

        // shoelace over valid vertices in (angle, index)-sorted cyclic order,
        // via successor search (identical to stable argsort + pad-with-first).
        float area2 = 0.0f;
#pragma unroll
        for (int k = 0; k < 24; k++) {
            if (!((valid >> k) & 1u)) continue;
            float ak = ang[k];
            float sAng = 1e30f, sxp = 0.0f, syp = 0.0f; int sIdx = 64; bool found = false;
            float gAng = 1e30f, gxp = 0.0f, gyp = 0.0f; int gIdx = 64;
#pragma unroll
            for (int j = 0; j < 24; j++) {
                if (!((valid >> j) & 1u)) continue;
                float aj = ang[j];
                bool greater = (aj > ak) || (aj == ak && j > k);
                if (greater && ((aj < sAng) || (aj == sAng && j < sIdx))) {
                    sAng = aj; sIdx = j; sxp = px[j]; syp = py[j]; found = true;
                }
                if ((aj < gAng) || (aj == gAng && j < gIdx)) {
                    gAng = aj; gIdx = j; gxp = px[j]; gyp = py[j];
                }
            }
            float qx = found ? sxp : gxp;
            float qy = found ? syp : gyp;
            area2 += px[k] * qy - qx * py[k];
        }
        inter_bev = 0.5f * fabsf(area2);
    }

    float inter = inter_bev * oh;
    float va = a[3] * a[4] * a[5];
    float vb = b[3] * b[4] * b[5];
    float den = fmaxf(va + vb - inter, 1e-6f);
    return inter / den;
}

// ---- Phase 0: init workspace (ws is re-poisoned to 0xAA before every call) ----
__global__ __launch_bounds__(256) void init_kernel(void* ws) {
    int t = blockIdx.x * blockDim.x + threadIdx.x;
    if (t == 0) *(int*)ws = 0;
    unsigned long long* best = (unsigned long long*)((char*)ws + BEST_OFF);
    if (t < NROI) best[t] = INIT_PACK;
}

// ---- Phase 1: cheap reject over all pairs, block-aggregated compaction ----
__global__ __launch_bounds__(256) void filter_kernel(
    const float* __restrict__ rois, const float* __restrict__ gts,
    void* ws, int capacity)
{
    __shared__ int lcount;
    __shared__ int lbase;
    if (threadIdx.x == 0) lcount = 0;
    __syncthreads();

    int p = blockIdx.x * blockDim.x + threadIdx.x;  // pair id, grid sized exactly
    bool pass = false;
    if (p < NPAIR) {
        int roi = p / NN;           // global roi index
        int n = p - roi * NN;
        int b = roi >> 10;          // RR = 1024
        float a[7], bx[7];
        const float* ap = rois + roi * 7;
        const float* bp = gts + (b * NN + n) * 8;
#pragma unroll
        for (int k = 0; k < 7; k++) a[k] = ap[k];
#pragma unroll
        for (int k = 0; k < 7; k++) bx[k] = bp[k];
        pass = cheap_pass(a, bx);
    }

    int my = -1;
    if (pass) my = atomicAdd(&lcount, 1);   // LDS atomic, fast
    __syncthreads();
    if (threadIdx.x == 0 && lcount > 0) lbase = atomicAdd((int*)ws, lcount);
    __syncthreads();
    if (pass) {
        int pos = lbase + my;
        if (pos < capacity) ((int*)((char*)ws + LIST_OFF))[pos] = p;
    }
}

// ---- Phase 2: dense exact IoU over survivors only, atomicMax reduce ----
__global__ __launch_bounds__(256) void iou_kernel(
    const float* __restrict__ rois, const float* __restrict__ gts,
    void* ws, int capacity)
{
    int count = *(volatile int*)ws;
    if (count > capacity) count = capacity;
    const int* list = (const int*)((char*)ws + LIST_OFF);
    unsigned long long* best = (unsigned long long*)((char*)ws + BEST_OFF);

    int stride = gridDim.x * blockDim.x;
    for (int i = blockIdx.x * blockDim.x + threadIdx.x; i < count; i += stride) {
        int p = list[i];
        int roi = p / NN;
        int n = p - roi * NN;
        int b = roi >> 10;
        float a[7], bx[7];
        const float* ap = rois + roi * 7;
        const float* bp = gts + (b * NN + n) * 8;
#pragma unroll
        for (int k = 0; k < 7; k++) a[k] = ap[k];
#pragma unroll
        for (int k = 0; k < 7; k++) bx[k] = bp[k];
        float v = iou3d_pair(a, bx);
        unsigned long long packed =
            ((unsigned long long)__float_as_uint(v) << 32) | (unsigned)(~(unsigned)n);
        atomicMax(&best[roi], packed);
    }
}

// ---- Phase 3: write the five outputs ----
__global__ __launch_bounds__(256) void epilogue_kernel(
    const float* __restrict__ rois, const int* __restrict__ labels,
    const float* __restrict__ gts, const void* __restrict__ ws,
    float* __restrict__ out)
{
    int r = blockIdx.x * blockDim.x + threadIdx.x;
    if (r >= NROI) return;
    int b = r >> 10;

    const unsigned long long* best = (const unsigned long long*)((const char*)ws + BEST_OFF);
    unsigned long long packed = best[r];
    float mo = __uint_as_float((unsigned)(packed >> 32));
    int besti = (int)(~(unsigned)(packed & 0xFFFFFFFFu));

    float* out_rois = out;                    // NROI*7
    float* out_gor  = out + NROI * 7;         // NROI*8
    float* out_max  = out_gor + NROI * 8;     // NROI
    float* out_lab  = out_max + NROI;         // NROI
    float* out_msk  = out_lab + NROI;         // NROI

    const float* ap = rois + r * 7;
#pragma unroll
    for (int k = 0; k < 7; k++) out_rois[r * 7 + k] = ap[k];
    const float* gp = gts + (b * NN + besti) * 8;
#pragma unroll
    for (int k = 0; k < 8; k++) out_gor[r * 8 + k] = gp[k];
    out_max[r] = mo;
    out_lab[r] = (float)labels[r];
    out_msk[r] = (mo > 0.55f) ? 1.0f : 0.0f;
}

extern "C" void kernel_launch(void* const* d_in, const int* in_sizes, int n_in,
                              void* d_out, int out_size, void* d_ws, size_t ws_size,
                              hipStream_t stream) {
    const float* rois   = (const float*)d_in[0];  // (4,1024,7) f32
    const int*   labels = (const int*)d_in[1];    // (4,1024) i32
    const float* gts    = (const float*)d_in[2];  // (4,100,8) f32
    float* out = (float*)d_out;

    int capacity = (int)((ws_size > (size_t)LIST_OFF) ? (ws_size - LIST_OFF) / 4 : 0);
    if (capacity > NPAIR) capacity = NPAIR;

    hipLaunchKernelGGL(init_kernel, dim3((NROI + 255) / 256), dim3(256), 0, stream, d_ws);
    hipLaunchKernelGGL(filter_kernel, dim3(NPAIR / 256), dim3(256), 0, stream,
                       rois, gts, d_ws, capacity);
    hipLaunchKernelGGL(iou_kernel, dim3(256), dim3(256), 0, stream,
                       rois, gts, d_ws, capacity);
    hipLaunchKernelGGL(epilogue_kernel, dim3((NROI + 255) / 256), dim3(256), 0, stream,
                       rois, labels, gts, d_ws, out);
}

// Round 3
// 128.580 us; speedup vs baseline: 1.2417x; 1.2417x over previous
//
#include <hip/hip_runtime.h>
#include <math.h>

#define BB 4
#define RR 1024
#define NN 100
#define NROI (BB * RR)
#define ROIS_PER_BLOCK 32
#define PAIRS_PER_BLOCK (ROIS_PER_BLOCK * NN)   // 3200
#define NBLOCKS (NROI / ROIS_PER_BLOCK)         // 128

// packed best: high 32 = float bits of IoU (>=0, monotone), low 32 = ~gt_idx
// => atomicMax picks highest IoU; on exact tie, smallest gt index (argmax semantics).
#define INIT_PACK 0x00000000FFFFFFFFull

__device__ __forceinline__ bool cheap_pass(const float a[7], const float b[7]) {
    float oh = fminf(a[2] + a[5] * 0.5f, b[2] + b[5] * 0.5f)
             - fmaxf(a[2] - a[5] * 0.5f, b[2] - b[5] * 0.5f);
    float dxc = a[0] - b[0], dyc = a[1] - b[1];
    float ra = 0.5f * sqrtf(a[3] * a[3] + a[4] * a[4]);
    float rb = 0.5f * sqrtf(b[3] * b[3] + b[4] * b[4]);
    float rr = ra + rb;
    return (oh > 0.0f) && (dxc * dxc + dyc * dyc <= rr * rr);
}

// Exact rotated-rect BEV intersection + 3D IoU — identical math to the R1 passing kernel.
__device__ __forceinline__ float iou3d_pair(const float a[7], const float b[7]) {
    float oh = fminf(a[2] + a[5] * 0.5f, b[2] + b[5] * 0.5f)
             - fmaxf(a[2] - a[5] * 0.5f, b[2] - b[5] * 0.5f);
    float dxc = a[0] - b[0], dyc = a[1] - b[1];
    float ra = 0.5f * sqrtf(a[3] * a[3] + a[4] * a[4]);
    float rb = 0.5f * sqrtf(b[3] * b[3] + b[4] * b[4]);
    float rr = ra + rb;
    if (oh <= 0.0f || dxc * dxc + dyc * dyc > rr * rr) return 0.0f;

    float ac = cosf(a[6]), as_ = sinf(a[6]);
    float bc = cosf(b[6]), bs_ = sinf(b[6]);

    const float lxs[4] = {0.5f, -0.5f, -0.5f, 0.5f};
    const float lys[4] = {0.5f,  0.5f, -0.5f, -0.5f};
    float cax[4], cay[4], cbx[4], cby[4];
#pragma unroll
    for (int i = 0; i < 4; i++) {
        float lx = lxs[i] * a[3], ly = lys[i] * a[4];
        cax[i] = a[0] + lx * ac - ly * as_;
        cay[i] = a[1] + lx * as_ + ly * ac;
        float mx = lxs[i] * b[3], my = lys[i] * b[4];
        cbx[i] = b[0] + mx * bc - my * bs_;
        cby[i] = b[1] + mx * bs_ + my * bc;
    }

    float px[24], py[24];
    unsigned valid = 0u;

#pragma unroll
    for (int i = 0; i < 4; i++) {
        px[i] = cax[i]; py[i] = cay[i];
        float qx = cax[i] - b[0], qy = cay[i] - b[1];
        float lx = qx * bc + qy * bs_;
        float ly = -qx * bs_ + qy * bc;
        if (fabsf(lx) <= b[3] * 0.5f + 1e-5f && fabsf(ly) <= b[4] * 0.5f + 1e-5f)
            valid |= 1u << i;
    }
#pragma unroll
    for (int i = 0; i < 4; i++) {
        px[4 + i] = cbx[i]; py[4 + i] = cby[i];
        float qx = cbx[i] - a[0], qy = cby[i] - a[1];
        float lx = qx * ac + qy * as_;
        float ly = -qx * as_ + qy * ac;
        if (fabsf(lx) <= a[3] * 0.5f + 1e-5f && fabsf(ly) <= a[4] * 0.5f + 1e-5f)
            valid |= 1u << (4 + i);
    }
#pragma unroll
    for (int i = 0; i < 4; i++) {
        float a1x = cax[i], a1y = cay[i];
        float d1x = cax[(i + 1) & 3] - a1x, d1y = cay[(i + 1) & 3] - a1y;
#pragma unroll
        for (int j = 0; j < 4; j++) {
            float b1x = cbx[j], b1y = cby[j];
            float d2x = cbx[(j + 1) & 3] - b1x, d2y = cby[(j + 1) & 3] - b1y;
            float denom = d1x * d2y - d1y * d2x;
            float fx = b1x - a1x, fy = b1y - a1y;
            float safe = (fabsf(denom) > 1e-8f) ? denom : 1e-8f;
            float t = (fx * d2y - fy * d2x) / safe;
            float u = (fx * d1y - fy * d1x) / safe;
            int k = 8 + i * 4 + j;
            px[k] = a1x + t * d1x;
            py[k] = a1y + t * d1y;
            if (fabsf(denom) > 1e-8f && t >= 0.0f && t <= 1.0f && u >= 0.0f && u <= 1.0f)
                valid |= 1u << k;
        }
    }

    int nv = __popc(valid);
    float inter_bev = 0.0f;
    if (nv >= 3) {
        float sx = 0.0f, sy = 0.0f;
#pragma unroll
        for (int k = 0; k < 24; k++) {
            if ((valid >> k) & 1u) { sx += px[k]; sy += py[k]; }
        }
        float cx = sx / (float)nv, cy = sy / (float)nv;

        float ang[24];
#pragma unroll
        for (int k = 0; k < 24; k++) {
            ang[k] = ((valid >> k) & 1u) ? atan2f(py[k] - cy, px[k] - cx) : 1e9f;
        }

        // shoelace over valid vertices in (angle, index)-sorted cyclic order,
        // via successor search (identical to stable argsort + pad-with-first).
        float area2 = 0.0f;
#pragma unroll
        for (int k = 0; k < 24; k++) {
            if (!((valid >> k) & 1u)) continue;
            float ak = ang[k];
            float sAng = 1e30f, sxp = 0.0f, syp = 0.0f; int sIdx = 64; bool found = false;
            float gAng = 1e30f, gxp = 0.0f, gyp = 0.0f; int gIdx = 64;
#pragma unroll
            for (int j = 0; j < 24; j++) {
                if (!((valid >> j) & 1u)) continue;
                float aj = ang[j];
                bool greater = (aj > ak) || (aj == ak && j > k);
                if (greater && ((aj < sAng) || (aj == sAng && j < sIdx))) {
                    sAng = aj; sIdx = j; sxp = px[j]; syp = py[j]; found = true;
                }
                if ((aj < gAng) || (aj == gAng && j < gIdx)) {
                    gAng = aj; gIdx = j; gxp = px[j]; gyp = py[j];
                }
            }
            float qx = found ? sxp : gxp;
            float qy = found ? syp : gyp;
            area2 += px[k] * qy - qx * py[k];
        }
        inter_bev = 0.5f * fabsf(area2);
    }

    float inter = inter_bev * oh;
    float va = a[3] * a[4] * a[5];
    float vb = b[3] * b[4] * b[5];
    float den = fmaxf(va + vb - inter, 1e-6f);
    return inter / den;
}

// One fused kernel: block owns 32 ROIs of one batch. Stage GTs+ROIs in LDS,
// cheap-filter 3200 pairs -> LDS worklist, dense-eval survivors, LDS atomicMax
// reduce, write all outputs. __launch_bounds__(256,1): VGPR budget up to 512
// so the 24-vertex polygon arrays stay in registers (R2's 88-VGPR spill was
// the 84us pathology).
__global__ __launch_bounds__(256, 1) void sampling_target_fused(
    const float* __restrict__ rois,   // (B,R,7)
    const int*   __restrict__ labels, // (B,R)
    const float* __restrict__ gts,    // (B,N,8)
    float*       __restrict__ out)
{
    __shared__ float s_gts[NN * 8];                       // 3200 B
    __shared__ float s_rois[ROIS_PER_BLOCK * 7];          // 896 B
    __shared__ int   s_list[PAIRS_PER_BLOCK];             // 12.8 KB (cannot overflow)
    __shared__ int   s_cnt;
    __shared__ unsigned long long s_best[ROIS_PER_BLOCK]; // 256 B

    const int tid = threadIdx.x;
    const int roi0 = blockIdx.x * ROIS_PER_BLOCK;   // global roi base
    const int b = roi0 >> 10;                       // RR=1024; 1024%32==0 -> whole block same batch

    // stage
    for (int i = tid; i < NN * 8; i += 256) s_gts[i] = gts[b * NN * 8 + i];
    for (int i = tid; i < ROIS_PER_BLOCK * 7; i += 256) s_rois[i] = rois[roi0 * 7 + i];
    if (tid < ROIS_PER_BLOCK) s_best[tid] = INIT_PACK;
    if (tid == 0) s_cnt = 0;
    __syncthreads();

    // Phase A: cheap reject + LDS compaction
    for (int p = tid; p < PAIRS_PER_BLOCK; p += 256) {
        int rl = p / NN;
        int n = p - rl * NN;
        float a[7], bx[7];
#pragma unroll
        for (int k = 0; k < 7; k++) a[k] = s_rois[rl * 7 + k];
#pragma unroll
        for (int k = 0; k < 7; k++) bx[k] = s_gts[n * 8 + k];
        if (cheap_pass(a, bx)) {
            int pos = atomicAdd(&s_cnt, 1);
            s_list[pos] = p;
        }
    }
    __syncthreads();

    // Phase B: dense exact IoU over survivors only
    const int cnt = s_cnt;
    for (int i = tid; i < cnt; i += 256) {
        int p = s_list[i];
        int rl = p / NN;
        int n = p - rl * NN;
        float a[7], bx[7];
#pragma unroll
        for (int k = 0; k < 7; k++) a[k] = s_rois[rl * 7 + k];
#pragma unroll
        for (int k = 0; k < 7; k++) bx[k] = s_gts[n * 8 + k];
        float v = iou3d_pair(a, bx);
        unsigned long long packed =
            ((unsigned long long)__float_as_uint(v) << 32) | (unsigned)(~(unsigned)n);
        atomicMax(&s_best[rl], packed);
    }
    __syncthreads();

    // Phase C: outputs
    if (tid < ROIS_PER_BLOCK) {
        int r = roi0 + tid;
        unsigned long long packed = s_best[tid];
        float mo = __uint_as_float((unsigned)(packed >> 32));
        int besti = (int)(~(unsigned)(packed & 0xFFFFFFFFu));

        float* out_rois = out;                    // NROI*7
        float* out_gor  = out + NROI * 7;         // NROI*8
        float* out_max  = out_gor + NROI * 8;     // NROI
        float* out_lab  = out_max + NROI;         // NROI
        float* out_msk  = out_lab + NROI;         // NROI

#pragma unroll
        for (int k = 0; k < 7; k++) out_rois[r * 7 + k] = s_rois[tid * 7 + k];
#pragma unroll
        for (int k = 0; k < 8; k++) out_gor[r * 8 + k] = s_gts[besti * 8 + k];
        out_max[r] = mo;
        out_lab[r] = (float)labels[r];
        out_msk[r] = (mo > 0.55f) ? 1.0f : 0.0f;
    }
}

extern "C" void kernel_launch(void* const* d_in, const int* in_sizes, int n_in,
                              void* d_out, int out_size, void* d_ws, size_t ws_size,
                              hipStream_t stream) {
    const float* rois   = (const float*)d_in[0];  // (4,1024,7) f32
    const int*   labels = (const int*)d_in[1];    // (4,1024) i32
    const float* gts    = (const float*)d_in[2];  // (4,100,8) f32
    float* out = (float*)d_out;

    hipLaunchKernelGGL(sampling_target_fused, dim3(NBLOCKS), dim3(256), 0, stream,
                       rois, labels, gts, out);
}

// Round 4
// 79.659 us; speedup vs baseline: 2.0043x; 1.6141x over previous
//
#include <hip/hip_runtime.h>
#include <math.h>

#define BB 4
#define RR 1024
#define NN 100
#define NROI (BB * RR)
#define RPB 16                     // ROIs per block
#define PPB (RPB * NN)             // 1600 pairs per block
#define NBLK (NROI / RPB)          // 256 blocks

// packed best: high 32 = float bits of IoU (>=0, monotone), low 32 = ~gt_idx
// => atomicMax picks highest IoU; on exact tie, smallest gt index (argmax-first semantics).
#define INIT_PACK 0x00000000FFFFFFFFull

// corner i of a rect (cx0,cy0,dx,dy,cos,sin); sign conv. matches reference
// lxs=[.5,-.5,-.5,.5], lys=[.5,.5,-.5,-.5]
__device__ __forceinline__ void corner_of(int i, float cx0, float cy0, float dx, float dy,
                                          float c, float s, float& X, float& Y) {
    float sx = (i == 0 || i == 3) ? 0.5f : -0.5f;
    float sy = (i <= 1) ? 0.5f : -0.5f;
    float lx = sx * dx, ly = sy * dy;
    X = cx0 + lx * c - ly * s;
    Y = cy0 + lx * s + ly * c;
}

// One fused kernel. Block owns 16 ROIs of one batch (1024%16==0).
// Phase A: cheap z/circle reject over 1600 pairs -> LDS worklist.
// Phase B: one surviving pair per 32-lane half-wave; the 24 polygon vertex
//          candidates live one-per-lane (NO local arrays -> no scratch, the
//          R2/R3 pathology). Successor search = 24 shfl-broadcast iterations;
//          centroid/shoelace = shfl_xor butterflies. LDS atomicMax reduce.
// Phase C: 16 threads write the five outputs.
__global__ __launch_bounds__(256) void sampling_target_fused(
    const float* __restrict__ rois,   // (B,R,7)
    const int*   __restrict__ labels, // (B,R)
    const float* __restrict__ gts,    // (B,N,8)
    float*       __restrict__ out)
{
    __shared__ float s_gts[NN * 9];            // stride 9 (coprime w/ 32 banks)
    __shared__ float s_rois[RPB * 7];          // stride 7 (coprime w/ 32 banks)
    __shared__ int   s_list[PPB];
    __shared__ int   s_cnt;
    __shared__ unsigned long long s_best[RPB];

    const int tid = threadIdx.x;
    const int roi0 = blockIdx.x * RPB;
    const int b = roi0 >> 10;                  // RR = 1024

    // ---- stage ----
    for (int i = tid; i < NN * 8; i += 256)
        s_gts[(i >> 3) * 9 + (i & 7)] = gts[b * NN * 8 + i];
    for (int i = tid; i < RPB * 7; i += 256)
        s_rois[i] = rois[roi0 * 7 + i];
    if (tid < RPB) s_best[tid] = INIT_PACK;
    if (tid == 0) s_cnt = 0;
    __syncthreads();

    // ---- Phase A: cheap reject + compaction ----
    for (int p = tid; p < PPB; p += 256) {
        int rl = p / NN;
        int n = p - rl * NN;
        const float* A = &s_rois[rl * 7];
        const float* G = &s_gts[n * 9];
        float oh = fminf(A[2] + A[5] * 0.5f, G[2] + G[5] * 0.5f)
                 - fmaxf(A[2] - A[5] * 0.5f, G[2] - G[5] * 0.5f);
        float dxc = A[0] - G[0], dyc = A[1] - G[1];
        float ra = 0.5f * sqrtf(A[3] * A[3] + A[4] * A[4]);
        float rb = 0.5f * sqrtf(G[3] * G[3] + G[4] * G[4]);
        float rr = ra + rb;
        if (oh > 0.0f && dxc * dxc + dyc * dyc <= rr * rr) {
            int pos = atomicAdd(&s_cnt, 1);
            s_list[pos] = p;   // capacity PPB: cannot overflow
        }
    }
    __syncthreads();

    // ---- Phase B: lane-parallel exact IoU, one pair per 32-lane group ----
    const int cnt = s_cnt;
    const int g = tid >> 5;          // 8 groups per block
    const int lane = tid & 31;
    const int half = (tid >> 5) & 1; // which half of the wave64

    for (int i = g; i < cnt; i += 8) {
        int p = s_list[i];
        int rl = p / NN;
        int n = p - rl * NN;
        const float* A = &s_rois[rl * 7];   // broadcast reads: no conflicts
        const float* G = &s_gts[n * 9];
        float ax = A[0], ay = A[1], az = A[2], adx = A[3], ady = A[4], adz = A[5], aang = A[6];
        float gx_ = G[0], gy_ = G[1], gz_ = G[2], gdx = G[3], gdy = G[4], gdz = G[5], gang = G[6];
        float acs = cosf(aang), asn = sinf(aang);
        float bcs = cosf(gang), bsn = sinf(gang);

        // my candidate vertex (lane -> reference slot k, same ordering)
        float ppx = 0.0f, ppy = 0.0f;
        bool val = false;
        if (lane < 4) {                       // corners of A, tested inside B
            corner_of(lane, ax, ay, adx, ady, acs, asn, ppx, ppy);
            float qx = ppx - gx_, qy = ppy - gy_;
            float lx = qx * bcs + qy * bsn;
            float ly = -qx * bsn + qy * bcs;
            val = (fabsf(lx) <= gdx * 0.5f + 1e-5f) && (fabsf(ly) <= gdy * 0.5f + 1e-5f);
        } else if (lane < 8) {                // corners of B, tested inside A
            corner_of(lane - 4, gx_, gy_, gdx, gdy, bcs, bsn, ppx, ppy);
            float qx = ppx - ax, qy = ppy - ay;
            float lx = qx * acs + qy * asn;
            float ly = -qx * asn + qy * acs;
            val = (fabsf(lx) <= adx * 0.5f + 1e-5f) && (fabsf(ly) <= ady * 0.5f + 1e-5f);
        } else if (lane < 24) {               // edge i of A x edge j of B
            int e = lane - 8;
            int ii = e >> 2, jj = e & 3;
            float a1x, a1y, a2x, a2y, b1x, b1y, b2x, b2y;
            corner_of(ii, ax, ay, adx, ady, acs, asn, a1x, a1y);
            corner_of((ii + 1) & 3, ax, ay, adx, ady, acs, asn, a2x, a2y);
            corner_of(jj, gx_, gy_, gdx, gdy, bcs, bsn, b1x, b1y);
            corner_of((jj + 1) & 3, gx_, gy_, gdx, gdy, bcs, bsn, b2x, b2y);
            float d1x = a2x - a1x, d1y = a2y - a1y;
            float d2x = b2x - b1x, d2y = b2y - b1y;
            float denom = d1x * d2y - d1y * d2x;
            float fx = b1x - a1x, fy = b1y - a1y;
            float safe = (fabsf(denom) > 1e-8f) ? denom : 1e-8f;
            float t = (fx * d2y - fy * d2x) / safe;
            float u = (fx * d1y - fy * d1x) / safe;
            ppx = a1x + t * d1x;
            ppy = a1y + t * d1y;
            val = (fabsf(denom) > 1e-8f) && (t >= 0.0f) && (t <= 1.0f) && (u >= 0.0f) && (u <= 1.0f);
        }

        unsigned long long m = __ballot(val);
        unsigned gm = (unsigned)(half ? (m >> 32) : (m & 0xFFFFFFFFull));
        int nv = __popc(gm);

        float inter_bev = 0.0f;
        if (nv >= 3) {   // group-uniform branch; width-32 shuffles safe inside
            // centroid over valid candidates
            float sx = val ? ppx : 0.0f;
            float sy = val ? ppy : 0.0f;
#pragma unroll
            for (int off = 16; off; off >>= 1) {
                sx += __shfl_xor(sx, off, 32);
                sy += __shfl_xor(sy, off, 32);
            }
            float cx = sx / (float)nv, cy = sy / (float)nv;

            float myAng = val ? atan2f(ppy - cy, ppx - cx) : 1e9f;

            // successor in (angle, index) order; fallback = global min.
            // ascending j + strict < == reference's stable-sort tie rules.
            float sAng = 1e30f, sqx = 0.0f, sqy = 0.0f;
            float gAng = 1e30f, gqx = 0.0f, gqy = 0.0f;
            bool found = false;
#pragma unroll
            for (int j = 0; j < 24; j++) {
                float aj = __shfl(myAng, j, 32);
                float xj = __shfl(ppx, j, 32);
                float yj = __shfl(ppy, j, 32);
                if (aj < 1e8f) {   // valid j only
                    bool greater = (aj > myAng) || (aj == myAng && j > lane);
                    if (greater && aj < sAng) { sAng = aj; sqx = xj; sqy = yj; found = true; }
                    if (aj < gAng) { gAng = aj; gqx = xj; gqy = yj; }
                }
            }
            float qx = found ? sqx : gqx;
            float qy = found ? sqy : gqy;
            float contrib = val ? (ppx * qy - qx * ppy) : 0.0f;
#pragma unroll
            for (int off = 16; off; off >>= 1)
                contrib += __shfl_xor(contrib, off, 32);
            inter_bev = 0.5f * fabsf(contrib);
        }

        if (lane == 0) {
            float oh = fminf(az + adz * 0.5f, gz_ + gdz * 0.5f)
                     - fmaxf(az - adz * 0.5f, gz_ - gdz * 0.5f);   // >0 by Phase A
            float inter = inter_bev * oh;
            float va = adx * ady * adz;
            float vb = gdx * gdy * gdz;
            float v = inter / fmaxf(va + vb - inter, 1e-6f);
            unsigned long long packed =
                ((unsigned long long)__float_as_uint(v) << 32) | (unsigned)(~(unsigned)n);
            atomicMax(&s_best[rl], packed);
        }
    }
    __syncthreads();

    // ---- Phase C: outputs ----
    if (tid < RPB) {
        int r = roi0 + tid;
        unsigned long long packed = s_best[tid];
        float mo = __uint_as_float((unsigned)(packed >> 32));
        int besti = (int)(~(unsigned)(packed & 0xFFFFFFFFu));

        float* out_rois = out;                    // NROI*7
        float* out_gor  = out + NROI * 7;         // NROI*8
        float* out_max  = out_gor + NROI * 8;     // NROI
        float* out_lab  = out_max + NROI;         // NROI
        float* out_msk  = out_lab + NROI;         // NROI

#pragma unroll
        for (int k = 0; k < 7; k++) out_rois[r * 7 + k] = s_rois[tid * 7 + k];
#pragma unroll
        for (int k = 0; k < 8; k++) out_gor[r * 8 + k] = s_gts[besti * 9 + k];
        out_max[r] = mo;
        out_lab[r] = (float)labels[r];
        out_msk[r] = (mo > 0.55f) ? 1.0f : 0.0f;
    }
}

extern "C" void kernel_launch(void* const* d_in, const int* in_sizes, int n_in,
                              void* d_out, int out_size, void* d_ws, size_t ws_size,
                              hipStream_t stream) {
    const float* rois   = (const float*)d_in[0];  // (4,1024,7) f32
    const int*   labels = (const int*)d_in[1];    // (4,1024) i32
    const float* gts    = (const float*)d_in[2];  // (4,100,8) f32
    float* out = (float*)d_out;

    hipLaunchKernelGGL(sampling_target_fused, dim3(NBLK), dim3(256), 0, stream,
                       rois, labels, gts, out);
}

// Round 5
// 67.750 us; speedup vs baseline: 2.3566x; 1.1758x over previous
//
#include <hip/hip_runtime.h>
#include <math.h>

#define BB 4
#define RR 1024
#define NN 100
#define NROI (BB * RR)
#define RPB 4                      // ROIs per block (small => 4 blocks/CU => latency hiding)
#define PPB (RPB * NN)             // 400 pairs per block
#define NBLK (NROI / RPB)          // 1024 blocks

// packed best: high 32 = float bits of IoU (>=0, monotone), low 32 = ~gt_idx
// => atomicMax picks highest IoU; on exact tie, smallest gt index (argmax-first semantics).
#define INIT_PACK 0x00000000FFFFFFFFull

// corner i of a rect; sign conv. matches reference lxs=[.5,-.5,-.5,.5], lys=[.5,.5,-.5,-.5]
__device__ __forceinline__ void corner_of(int i, float cx0, float cy0, float dx, float dy,
                                          float c, float s, float& X, float& Y) {
    float sx = (i == 0 || i == 3) ? 0.5f : -0.5f;
    float sy = (i <= 1) ? 0.5f : -0.5f;
    float lx = sx * dx, ly = sy * dy;
    X = cx0 + lx * c - ly * s;
    Y = cy0 + lx * s + ly * c;
}

// Fused kernel. Block owns 4 ROIs of one batch (1024%4==0 -> no batch straddle).
// Phase A: cheap z/circle reject over 400 pairs -> LDS worklist (compaction).
// Phase B: one surviving pair per 32-lane group; 24 polygon vertex candidates
//          live one-per-lane (no local arrays -> no scratch). Successor search:
//          24 angle-broadcast shuffles tracking INDEX only, then 2 shuffles to
//          fetch the successor point (26 bpermutes vs 72 in R4).
// Phase C: 4 threads write the five outputs.
__global__ __launch_bounds__(256) void sampling_target_fused(
    const float* __restrict__ rois,   // (B,R,7)
    const int*   __restrict__ labels, // (B,R)
    const float* __restrict__ gts,    // (B,N,8)
    float*       __restrict__ out)
{
    __shared__ float s_gts[NN * 9];            // stride 9 (2-way-max bank aliasing: free)
    __shared__ float s_rois[RPB * 7];
    __shared__ int   s_list[PPB];
    __shared__ int   s_cnt;
    __shared__ unsigned long long s_best[RPB];

    const int tid = threadIdx.x;
    const int roi0 = blockIdx.x * RPB;
    const int b = roi0 >> 10;                  // RR = 1024

    // ---- stage ----
    for (int i = tid; i < NN * 8; i += 256)
        s_gts[(i >> 3) * 9 + (i & 7)] = gts[b * NN * 8 + i];
    if (tid < RPB * 7) s_rois[tid] = rois[roi0 * 7 + tid];
    if (tid < RPB) s_best[tid] = INIT_PACK;
    if (tid == 0) s_cnt = 0;
    __syncthreads();

    // ---- Phase A: cheap reject + compaction (400 pairs, <2 iters/thread) ----
    for (int p = tid; p < PPB; p += 256) {
        int rl = p / NN;
        int n = p - rl * NN;
        const float* A = &s_rois[rl * 7];
        const float* G = &s_gts[n * 9];
        float oh = fminf(A[2] + A[5] * 0.5f, G[2] + G[5] * 0.5f)
                 - fmaxf(A[2] - A[5] * 0.5f, G[2] - G[5] * 0.5f);
        float dxc = A[0] - G[0], dyc = A[1] - G[1];
        float ra = 0.5f * sqrtf(A[3] * A[3] + A[4] * A[4]);
        float rb = 0.5f * sqrtf(G[3] * G[3] + G[4] * G[4]);
        float rr = ra + rb;
        if (oh > 0.0f && dxc * dxc + dyc * dyc <= rr * rr) {
            int pos = atomicAdd(&s_cnt, 1);
            s_list[pos] = p;   // capacity PPB: cannot overflow
        }
    }
    __syncthreads();

    // ---- Phase B: lane-parallel exact IoU, one pair per 32-lane group ----
    const int cnt = s_cnt;                     // ~7 expected => ~1 iter/group
    const int g = tid >> 5;                    // 8 groups per block
    const int lane = tid & 31;
    const int half = (tid >> 5) & 1;

    for (int i = g; i < cnt; i += 8) {
        int p = s_list[i];
        int rl = p / NN;
        int n = p - rl * NN;
        const float* A = &s_rois[rl * 7];      // group-broadcast LDS reads
        const float* G = &s_gts[n * 9];
        float ax = A[0], ay = A[1], az = A[2], adx = A[3], ady = A[4], adz = A[5], aang = A[6];
        float gx_ = G[0], gy_ = G[1], gz_ = G[2], gdx = G[3], gdy = G[4], gdz = G[5], gang = G[6];
        float acs = cosf(aang), asn = sinf(aang);
        float bcs = cosf(gang), bsn = sinf(gang);

        // my candidate vertex (lane -> reference slot k, same ordering)
        float ppx = 0.0f, ppy = 0.0f;
        bool val = false;
        if (lane < 4) {                        // corners of A, tested inside B
            corner_of(lane, ax, ay, adx, ady, acs, asn, ppx, ppy);
            float qx = ppx - gx_, qy = ppy - gy_;
            float lx = qx * bcs + qy * bsn;
            float ly = -qx * bsn + qy * bcs;
            val = (fabsf(lx) <= gdx * 0.5f + 1e-5f) && (fabsf(ly) <= gdy * 0.5f + 1e-5f);
        } else if (lane < 8) {                 // corners of B, tested inside A
            corner_of(lane - 4, gx_, gy_, gdx, gdy, bcs, bsn, ppx, ppy);
            float qx = ppx - ax, qy = ppy - ay;
            float lx = qx * acs + qy * asn;
            float ly = -qx * asn + qy * acs;
            val = (fabsf(lx) <= adx * 0.5f + 1e-5f) && (fabsf(ly) <= ady * 0.5f + 1e-5f);
        } else if (lane < 24) {                // edge i of A x edge j of B
            int e = lane - 8;
            int ii = e >> 2, jj = e & 3;
            float a1x, a1y, a2x, a2y, b1x, b1y, b2x, b2y;
            corner_of(ii, ax, ay, adx, ady, acs, asn, a1x, a1y);
            corner_of((ii + 1) & 3, ax, ay, adx, ady, acs, asn, a2x, a2y);
            corner_of(jj, gx_, gy_, gdx, gdy, bcs, bsn, b1x, b1y);
            corner_of((jj + 1) & 3, gx_, gy_, gdx, gdy, bcs, bsn, b2x, b2y);
            float d1x = a2x - a1x, d1y = a2y - a1y;
            float d2x = b2x - b1x, d2y = b2y - b1y;
            float denom = d1x * d2y - d1y * d2x;
            float fx = b1x - a1x, fy = b1y - a1y;
            float safe = (fabsf(denom) > 1e-8f) ? denom : 1e-8f;
            float t = (fx * d2y - fy * d2x) / safe;
            float u = (fx * d1y - fy * d1x) / safe;
            ppx = a1x + t * d1x;
            ppy = a1y + t * d1y;
            val = (fabsf(denom) > 1e-8f) && (t >= 0.0f) && (t <= 1.0f) && (u >= 0.0f) && (u <= 1.0f);
        }

        unsigned long long m = __ballot(val);
        unsigned gm = (unsigned)(half ? (m >> 32) : (m & 0xFFFFFFFFull));
        int nv = __popc(gm);

        float inter_bev = 0.0f;
        if (nv >= 3) {   // group-uniform branch; width-32 shuffles safe inside
            float sx = val ? ppx : 0.0f;
            float sy = val ? ppy : 0.0f;
#pragma unroll
            for (int off = 16; off; off >>= 1) {
                sx += __shfl_xor(sx, off, 32);
                sy += __shfl_xor(sy, off, 32);
            }
            float cx = sx / (float)nv, cy = sy / (float)nv;

            float myAng = val ? atan2f(ppy - cy, ppx - cx) : 1e9f;

            // successor in (angle, index) order, index-only tracking;
            // ascending j + strict < reproduces stable-argsort tie rules.
            float sAng = 1e30f; int sIdx = 0; bool found = false;
            float gAng = 1e30f; int gIdx = 0;
#pragma unroll
            for (int j = 0; j < 24; j++) {
                float aj = __shfl(myAng, j, 32);
                if (aj < 1e8f) {   // valid j only
                    bool greater = (aj > myAng) || (aj == myAng && j > lane);
                    if (greater && aj < sAng) { sAng = aj; sIdx = j; found = true; }
                    if (aj < gAng) { gAng = aj; gIdx = j; }
                }
            }
            int qi = found ? sIdx : gIdx;
            float qx = __shfl(ppx, qi, 32);
            float qy = __shfl(ppy, qi, 32);
            float contrib = val ? (ppx * qy - qx * ppy) : 0.0f;
#pragma unroll
            for (int off = 16; off; off >>= 1)
                contrib += __shfl_xor(contrib, off, 32);
            inter_bev = 0.5f * fabsf(contrib);
        }

        if (lane == 0) {
            float oh = fminf(az + adz * 0.5f, gz_ + gdz * 0.5f)
                     - fmaxf(az - adz * 0.5f, gz_ - gdz * 0.5f);   // >0 by Phase A
            float inter = inter_bev * oh;
            float va = adx * ady * adz;
            float vb = gdx * gdy * gdz;
            float v = inter / fmaxf(va + vb - inter, 1e-6f);
            unsigned long long packed =
                ((unsigned long long)__float_as_uint(v) << 32) | (unsigned)(~(unsigned)n);
            atomicMax(&s_best[rl], packed);
        }
    }
    __syncthreads();

    // ---- Phase C: outputs ----
    if (tid < RPB) {
        int r = roi0 + tid;
        unsigned long long packed = s_best[tid];
        float mo = __uint_as_float((unsigned)(packed >> 32));
        int besti = (int)(~(unsigned)(packed & 0xFFFFFFFFu));

        float* out_rois = out;                    // NROI*7
        float* out_gor  = out + NROI * 7;         // NROI*8
        float* out_max  = out_gor + NROI * 8;     // NROI
        float* out_lab  = out_max + NROI;         // NROI
        float* out_msk  = out_lab + NROI;         // NROI

#pragma unroll
        for (int k = 0; k < 7; k++) out_rois[r * 7 + k] = s_rois[tid * 7 + k];
#pragma unroll
        for (int k = 0; k < 8; k++) out_gor[r * 8 + k] = s_gts[besti * 9 + k];
        out_max[r] = mo;
        out_lab[r] = (float)labels[r];
        out_msk[r] = (mo > 0.55f) ? 1.0f : 0.0f;
    }
}

extern "C" void kernel_launch(void* const* d_in, const int* in_sizes, int n_in,
                              void* d_out, int out_size, void* d_ws, size_t ws_size,
                              hipStream_t stream) {
    const float* rois   = (const float*)d_in[0];  // (4,1024,7) f32
    const int*   labels = (const int*)d_in[1];    // (4,1024) i32
    const float* gts    = (const float*)d_in[2];  // (4,100,8) f32
    float* out = (float*)d_out;

    hipLaunchKernelGGL(sampling_target_fused, dim3(NBLK), dim3(256), 0, stream,
                       rois, labels, gts, out);
}